// Round 6
// baseline (24888.345 us; speedup 1.0000x reference)
//
#include <hip/hip_runtime.h>
#include <math.h>

// ---------------------------------------------------------------------------
// Types / helpers
// ---------------------------------------------------------------------------
typedef short bf16x8 __attribute__((ext_vector_type(8)));
typedef float f32x4 __attribute__((ext_vector_type(4)));
typedef int   i32x4 __attribute__((ext_vector_type(4)));

#define DEV static __device__ __forceinline__

DEV float bf2f(unsigned short u) {
  union { unsigned int i; float f; } x;
  x.i = ((unsigned int)u) << 16;
  return x.f;
}
DEV unsigned short f2bf(float f) {  // round-to-nearest-even
  union { float f; unsigned int i; } x;
  x.f = f;
  unsigned int i = x.i;
  i += 0x7fffu + ((i >> 16) & 1u);
  return (unsigned short)(i >> 16);
}
// Load 8 contiguous fp32, convert to 8 bf16 packed in an i32x4.
DEV i32x4 load8_cvt(const float* p) {
  const float4 x = *(const float4*)p;
  const float4 y = *(const float4*)(p + 4);
  union { i32x4 v; unsigned short u[8]; } r;
  r.u[0] = f2bf(x.x); r.u[1] = f2bf(x.y); r.u[2] = f2bf(x.z); r.u[3] = f2bf(x.w);
  r.u[4] = f2bf(y.x); r.u[5] = f2bf(y.y); r.u[6] = f2bf(y.z); r.u[7] = f2bf(y.w);
  return r.v;
}
DEV bf16x8 load8_cvt_frag(const float* p) {
  union { i32x4 v; bf16x8 h; } u;
  u.v = load8_cvt(p);
  return u.h;
}
DEV float tanh_fast(float x) {           // 1 - 2/(e^{2x}+1); exact at +-inf
  const float e = __expf(2.f * x);
  return 1.f - 2.f / (e + 1.f);
}
DEV float sigmoid_fast(float x) { return 1.f / (1.f + __expf(-x)); }

// ---------------------------------------------------------------------------
// Generic GEMM:  C[m,n] = act( escale*(A . B^T) + bias[n] ) ; MFMA in bf16.
// A: [M,K] row-major (lda); B: [N,K] row-major (ldb)  ("B^T" layout).
// AF32/BF32: operand stored fp32 (converted to bf16 in-register at staging).
// CF32: output fp32, else bf16.  bias is always fp32.
// 128x128 tile, BK=64, 4 waves, 4x4 MFMA 16x16x32, XOR-swizzled LDS.
// DUALA (bf16-A only): K=1024 split — kt<8 from A (lda), kt>=8 from A2 (512).
// TRANSC: C written V^T-style: idx=((row>>10)*512+col)*1024+(row&1023).
// ACT: 0=none 1=silu 2=sigmoid
// ---------------------------------------------------------------------------
template <int ACT, bool HASBIAS, bool DUALA, bool TRANSC,
          bool AF32, bool BF32, bool CF32>
__global__ __launch_bounds__(256) void gemm_bt(
    const void* __restrict__ A, long long sA, int lda,
    const unsigned short* __restrict__ A2,   // DUALA second source (bf16, ld=512)
    const void* __restrict__ B, long long sB, int ldb,
    const float* __restrict__ bias,
    void* __restrict__ Cout, long long sC,
    int M, int N, int K, float escale)
{
  __shared__ __align__(16) unsigned short Als[128 * 64];
  __shared__ __align__(16) unsigned short Bls[128 * 64];
  const int tid = threadIdx.x;
  const int l = tid & 63;
  const int w = tid >> 6;
  const int wrow = w >> 1, wcol = w & 1;
  const int lane15 = l & 15, quad = l >> 4;
  const long long tm0 = (long long)blockIdx.y * 128;
  const long long tn0 = (long long)blockIdx.x * 128;
  const long long zA = (long long)blockIdx.z * sA;
  const long long zB = (long long)blockIdx.z * sB;
  const float* Af          = (const float*)A;
  const unsigned short* Ah = (const unsigned short*)A;
  const float* Bf          = (const float*)B;
  const unsigned short* Bh = (const unsigned short*)B;

  f32x4 acc[4][4] = {};

  const int srow = tid >> 3;  // 0..31
  const int skb  = tid & 7;   // 0..7
  i32x4 ra[4], rb[4];

  auto gload = [&](int kt) {
    const long long k0 = (long long)kt * 64 + skb * 8;
#pragma unroll
    for (int it = 0; it < 4; ++it) {
      const int r = it * 32 + srow;
      if (DUALA && kt >= 8)
        ra[it] = *(const i32x4*)(A2 + (tm0 + r) * 512 + (k0 - 512));
      else if (AF32)
        ra[it] = load8_cvt(Af + zA + (tm0 + r) * lda + k0);
      else
        ra[it] = *(const i32x4*)(Ah + zA + (tm0 + r) * lda + k0);
      if (BF32)
        rb[it] = load8_cvt(Bf + zB + (tn0 + r) * ldb + k0);
      else
        rb[it] = *(const i32x4*)(Bh + zB + (tn0 + r) * ldb + k0);
    }
  };
  auto swrite = [&]() {
#pragma unroll
    for (int it = 0; it < 4; ++it) {
      const int r = it * 32 + srow;
      const int off = r * 64 + ((skb ^ (r & 7)) * 8);
      *(i32x4*)(Als + off) = ra[it];
      *(i32x4*)(Bls + off) = rb[it];
    }
  };

  gload(0);
  const int NK = K >> 6;
  for (int kt = 0; kt < NK; ++kt) {
    __syncthreads();
    swrite();
    __syncthreads();
    if (kt + 1 < NK) gload(kt + 1);
#pragma unroll
    for (int ks = 0; ks < 2; ++ks) {
      bf16x8 af[4], bfr[4];
#pragma unroll
      for (int ti = 0; ti < 4; ++ti) {
        const int m = wrow * 64 + ti * 16 + lane15;
        const int kb = ks * 4 + quad;
        af[ti] = *(const bf16x8*)(Als + m * 64 + ((kb ^ (m & 7)) * 8));
        const int n = wcol * 64 + ti * 16 + lane15;
        bfr[ti] = *(const bf16x8*)(Bls + n * 64 + ((kb ^ (n & 7)) * 8));
      }
#pragma unroll
      for (int ti = 0; ti < 4; ++ti)
#pragma unroll
        for (int tj = 0; tj < 4; ++tj)
          acc[ti][tj] = __builtin_amdgcn_mfma_f32_16x16x32_bf16(
              af[ti], bfr[tj], acc[ti][tj], 0, 0, 0);
    }
  }

  // Epilogue. C/D layout: col = lane&15, row = quad*4 + reg.
  const long long cb = (long long)blockIdx.z * sC;
#pragma unroll
  for (int tj = 0; tj < 4; ++tj) {
    const long long col = tn0 + wcol * 64 + tj * 16 + lane15;
    const float bvv = HASBIAS ? bias[col] : 0.f;
#pragma unroll
    for (int ti = 0; ti < 4; ++ti) {
#pragma unroll
      for (int r = 0; r < 4; ++r) {
        const long long row = tm0 + wrow * 64 + ti * 16 + quad * 4 + r;
        const long long idx =
            TRANSC ? (((row >> 10) * 512 + col) * 1024 + (row & 1023))
                   : (cb + row * (long long)N + col);
        float v = acc[ti][tj][r] * escale + bvv;
        if (ACT == 1) v = v / (1.f + __expf(-v));        // silu
        else if (ACT == 2) v = 1.f / (1.f + __expf(-v)); // sigmoid
        if (CF32) ((float*)Cout)[idx] = v;
        else      ((unsigned short*)Cout)[idx] = f2bf(v);
      }
    }
  }
}

// ---------------------------------------------------------------------------
// Transpose fp32 src -> bf16 dst with dst leading dim: dst[c*dld+r]=src[r*C+c]
// ---------------------------------------------------------------------------
__global__ __launch_bounds__(256) void transpose_f2b(
    const float* __restrict__ src, unsigned short* __restrict__ dst,
    int R, int C, int dld)
{
  __shared__ float tile[32][33];
  const int c0 = blockIdx.x * 32, r0 = blockIdx.y * 32;
  const int tx = threadIdx.x & 31, ty = threadIdx.x >> 5;
  for (int i = ty; i < 32; i += 8)
    tile[i][tx] = src[(long long)(r0 + i) * C + c0 + tx];
  __syncthreads();
  for (int i = ty; i < 32; i += 8)
    dst[(long long)(c0 + i) * dld + r0 + tx] = f2bf(tile[tx][i]);
}

// ---------------------------------------------------------------------------
// In-place row softmax over 1024 bf16 cols (scale applied upstream).
// Each thread owns its own ushort4 of its own row -> in-place is race-free.
// ---------------------------------------------------------------------------
__global__ __launch_bounds__(256) void softmax_rows_bf16(
    unsigned short* __restrict__ S)
{
  const long long row = blockIdx.x;
  const int tid = threadIdx.x;
  const ushort4 u = ((const ushort4*)(S + row * 1024))[tid];
  const float a = bf2f(u.x), b = bf2f(u.y), c = bf2f(u.z), d = bf2f(u.w);
  float mx = fmaxf(fmaxf(a, b), fmaxf(c, d));
#pragma unroll
  for (int o = 32; o > 0; o >>= 1) mx = fmaxf(mx, __shfl_xor(mx, o));
  __shared__ float redm[4], reds[4];
  const int w = tid >> 6;
  if ((tid & 63) == 0) redm[w] = mx;
  __syncthreads();
  mx = fmaxf(fmaxf(redm[0], redm[1]), fmaxf(redm[2], redm[3]));
  const float e0 = __expf(a - mx), e1 = __expf(b - mx);
  const float e2 = __expf(c - mx), e3 = __expf(d - mx);
  float s = e0 + e1 + e2 + e3;
#pragma unroll
  for (int o = 32; o > 0; o >>= 1) s += __shfl_xor(s, o);
  if ((tid & 63) == 0) reds[w] = s;
  __syncthreads();
  s = reds[0] + reds[1] + reds[2] + reds[3];
  const float inv = 1.f / s;
  ushort4 o4;
  o4.x = f2bf(e0 * inv); o4.y = f2bf(e1 * inv);
  o4.z = f2bf(e2 * inv); o4.w = f2bf(e3 * inv);
  ((ushort4*)(S + row * 1024))[tid] = o4;
}

// ---------------------------------------------------------------------------
// In-place z *= f (bf16, 4/thread). Per-element ownership -> race-free.
// ---------------------------------------------------------------------------
__global__ __launch_bounds__(256) void mul_bf16(
    unsigned short* __restrict__ z, const unsigned short* __restrict__ f, int n4)
{
  const int idx = blockIdx.x * 256 + threadIdx.x;
  if (idx >= n4) return;
  ushort4 zv = ((const ushort4*)z)[idx];
  const ushort4 fv = ((const ushort4*)f)[idx];
  zv.x = f2bf(bf2f(zv.x) * bf2f(fv.x));
  zv.y = f2bf(bf2f(zv.y) * bf2f(fv.y));
  zv.z = f2bf(bf2f(zv.z) * bf2f(fv.z));
  zv.w = f2bf(bf2f(zv.w) * bf2f(fv.w));
  ((ushort4*)z)[idx] = zv;
}

// ---------------------------------------------------------------------------
// B_h = i*ZC + (1-i)*b   (i,ZC bf16; b fp32; out bf16), 4 elems/thread
// ---------------------------------------------------------------------------
__global__ __launch_bounds__(256) void bh_blend(
    const unsigned short* __restrict__ ib, const unsigned short* __restrict__ zc,
    const float* __restrict__ bsrc, unsigned short* __restrict__ out, int n4)
{
  const int idx = blockIdx.x * 256 + threadIdx.x;
  if (idx >= n4) return;
  const ushort4 iv = ((const ushort4*)ib)[idx];
  const ushort4 zv = ((const ushort4*)zc)[idx];
  const float4 bv = ((const float4*)bsrc)[idx];
  ushort4 o;
  const float i0 = bf2f(iv.x), i1 = bf2f(iv.y), i2 = bf2f(iv.z), i3 = bf2f(iv.w);
  o.x = f2bf(i0 * bf2f(zv.x) + (1.f - i0) * bv.x);
  o.y = f2bf(i1 * bf2f(zv.y) + (1.f - i1) * bv.y);
  o.z = f2bf(i2 * bf2f(zv.z) + (1.f - i2) * bv.z);
  o.w = f2bf(i3 * bf2f(zv.w) + (1.f - i3) * bv.w);
  ((ushort4*)out)[idx] = o;
}

// ---------------------------------------------------------------------------
// EMA recurrence, round-6 rewrite: batch-split persistent kernel, NO global
// sync. 2 WGs x 1024 threads; WG owns batches [8*blk, 8*blk+8) — sequences
// are independent, so prev lives entirely in this WG's LDS; the per-step
// "sync" is two __syncthreads (round-5's cross-XCD flag handshake was
// ~5.6us/step of pure latency; intra-CU barriers are ~0.1us).
//
// 16 waves: gate g=w>>3 (0=alpha,1=delta), 64-col block cb=w&7. Full gate
// weights register-resident: wf[4][16] bf16x8 = 256 VGPRs/wave
// (16 waves x 64 cols x 512 k x 2B = 1MB total). MFMA floor: 1024
// mfma_16x16x32/step ~ 5.0K cyc ~ 2.1us/step (per-CU issue ceiling, m06).
// prev kept bf16 in swizzled LDS (rows 8..15 zeroed; their MFMA outputs are
// discarded — matmul rows are independent).
// ---------------------------------------------------------------------------
__global__ __launch_bounds__(1024, 4) void ema_recurrence(
    const float* __restrict__ Wa,            // fp32 [512][1024], k 0..511 used
    const float* __restrict__ Wd,
    const unsigned short* __restrict__ Xa,   // [16,1024,512] bf16 (bias folded)
    const unsigned short* __restrict__ Xd,
    const float* __restrict__ Bin,           // b: [16,1024,512] fp32
    unsigned short* __restrict__ ema)        // out: [16,1024,512] bf16
{
  const int b0 = blockIdx.x * 8;
  const int tid = threadIdx.x;
  const int l = tid & 63;
  const int w = tid >> 6;          // 0..15
  const int g = w >> 3;            // 0=alpha, 1=delta
  const int cbk = w & 7;           // 64-col block
  const int lane15 = l & 15;
  const int quad = l >> 4;
  const float* Wsel = g ? Wd : Wa;

  // Persistent weight fragments: B^T[n=cbk*64+tj*16+lane15][k=s*32+quad*8..]
  bf16x8 wf[4][16];
#pragma unroll
  for (int tj = 0; tj < 4; ++tj) {
    const long long ncol = cbk * 64 + tj * 16 + lane15;
#pragma unroll
    for (int s = 0; s < 16; ++s)
      wf[tj][s] = load8_cvt_frag(Wsel + ncol * 1024 + s * 32 + quad * 8);
  }

  __shared__ __align__(16) unsigned short lds_prev[16 * 512];  // swizzled bf16
  __shared__ __align__(16) float lds_g[2][8][512];

  // zero lds_prev (rows 8..15 stay zero forever; rows 0..7 rewritten each t)
  *(i32x4*)(lds_prev + tid * 8) = i32x4{0, 0, 0, 0};
  __syncthreads();

  // Elementwise mapping: 2 waves per batch; thread owns 4 cols.
  const int eb = w >> 1;                 // local batch 0..7
  const int c0 = (w & 1) * 256 + l * 4;  // col 0..511
  const int kb = c0 >> 3;
  const int pofs = eb * 512 + ((kb ^ (eb & 7)) << 3) + (c0 & 7);
  float pv0 = 0.f, pv1 = 0.f, pv2 = 0.f, pv3 = 0.f;  // exact fp32 prev

  const long long rowbase = (long long)(b0 + eb) * 1024 * 512 + c0;

  for (int t = 0; t < 1024; ++t) {
    const long long eidx = rowbase + (long long)t * 512;
    const ushort4 xa4 = *(const ushort4*)(Xa + eidx);   // issued up front;
    const ushort4 xd4 = *(const ushort4*)(Xd + eidx);   // consumed after the
    const float4  bv4 = *(const float4*)(Bin + eidx);   // MFMA phase

    f32x4 acc[4] = {};
    if (t > 0) {
#pragma unroll
      for (int s = 0; s < 16; ++s) {
        const int xk = (s * 4 + quad) ^ (lane15 & 7);
        const bf16x8 af = *(const bf16x8*)(lds_prev + lane15 * 512 + xk * 8);
#pragma unroll
        for (int tj = 0; tj < 4; ++tj)
          acc[tj] = __builtin_amdgcn_mfma_f32_16x16x32_bf16(
              af, wf[tj][s], acc[tj], 0, 0, 0);
      }
    }
    // C rows = quad*4+r: only rows 0..7 (quads 0,1) are real batches.
    if (quad < 2) {
#pragma unroll
      for (int tj = 0; tj < 4; ++tj)
#pragma unroll
        for (int r = 0; r < 4; ++r)
          lds_g[g][quad * 4 + r][cbk * 64 + tj * 16 + lane15] = acc[tj][r];
    }
    __syncthreads();

    const float4 av = *(const float4*)(&lds_g[0][eb][c0]);
    const float4 dv = *(const float4*)(&lds_g[1][eb][c0]);
    const float a0 = tanh_fast(av.x + bf2f(xa4.x));
    const float a1 = tanh_fast(av.y + bf2f(xa4.y));
    const float a2 = tanh_fast(av.z + bf2f(xa4.z));
    const float a3 = tanh_fast(av.w + bf2f(xa4.w));
    const float d0 = tanh_fast(dv.x + bf2f(xd4.x));
    const float d1 = tanh_fast(dv.y + bf2f(xd4.y));
    const float d2 = tanh_fast(dv.z + bf2f(xd4.z));
    const float d3 = tanh_fast(dv.w + bf2f(xd4.w));
    const float e0 = sigmoid_fast(a0 * bv4.x + (1.f - a0 * d0) * pv0);
    const float e1 = sigmoid_fast(a1 * bv4.y + (1.f - a1 * d1) * pv1);
    const float e2 = sigmoid_fast(a2 * bv4.z + (1.f - a2 * d2) * pv2);
    const float e3 = sigmoid_fast(a3 * bv4.w + (1.f - a3 * d3) * pv3);
    pv0 = e0; pv1 = e1; pv2 = e2; pv3 = e3;
    ushort4 o4;
    o4.x = f2bf(e0); o4.y = f2bf(e1); o4.z = f2bf(e2); o4.w = f2bf(e3);
    *(ushort4*)(ema + eidx) = o4;            // global out (stream-ordered)
    *(ushort4*)(lds_prev + pofs) = o4;       // next step's A operand
    __syncthreads();                         // lds_prev ready; lds_g reusable
  }
}

// ---------------------------------------------------------------------------
// Host. ALL inputs fp32, output fp32. Intermediates bf16.
// Workspace peak ~57 MB; d_out (32MB fp32) doubles as bf16 scratch for
// V^T then Z_EMA_C before the final fp32 GEMM overwrites it.
// Slot lifetimes:
//   S1: Xa  -> b_ema
//   S2: Xd  -> Q  -> Z_EMA (per-group) -> B_h
//   S3: EMA -> K  -> f -> i
//   SC (8MB): scores for 4 batches at a time
// ---------------------------------------------------------------------------
extern "C" void kernel_launch(void* const* d_in, const int* in_sizes, int n_in,
                              void* d_out, int out_size, void* d_ws, size_t ws_size,
                              hipStream_t stream)
{
  (void)in_sizes; (void)n_in; (void)out_size; (void)ws_size;
  typedef const float* cfp;
  cfp b     = (cfp)d_in[0];
  cfp Wq    = (cfp)d_in[1];  cfp bq   = (cfp)d_in[2];
  cfp Wk    = (cfp)d_in[3];  cfp bk   = (cfp)d_in[4];
  cfp Wv    = (cfp)d_in[5];  cfp bv   = (cfp)d_in[6];
  cfp Wa    = (cfp)d_in[7];  cfp ba   = (cfp)d_in[8];
  cfp Wd    = (cfp)d_in[9];  cfp bd   = (cfp)d_in[10];
  cfp Wout  = (cfp)d_in[11]; cfp bout = (cfp)d_in[12];
  cfp Wf    = (cfp)d_in[13]; cfp bfb  = (cfp)d_in[14];
  cfp Wemac = (cfp)d_in[15];
  cfp Wzc   = (cfp)d_in[16]; cfp bC   = (cfp)d_in[17];
  cfp Wi    = (cfp)d_in[18]; cfp bi   = (cfp)d_in[19];
  cfp Wo    = (cfp)d_in[20]; cfp bo   = (cfp)d_in[21];

  char* ws = (char*)d_ws;
  const size_t MB = 1024ull * 1024ull;
  typedef unsigned short* bfp;
  bfp S1    = (bfp)(ws + 0);        // 16MB
  bfp S2    = (bfp)(ws + 16 * MB);  // 16MB
  bfp S3    = (bfp)(ws + 32 * MB);  // 16MB
  bfp SC    = (bfp)(ws + 48 * MB);  // 8MB (scores, 4 batches)
  bfp W2    = (bfp)(ws + 56 * MB);  // 1MB combined bf16 [512n][1024k]
  bfp OUTH  = (bfp)d_out;           // bf16 scratch view: V^T, then Z_EMA_C

  // Combined weight (bf16) for the dual-A GEMM: W2[n][k<512]=Wzc[k][n],
  // W2[n][512+k]=Wemac[k][n].
  transpose_f2b<<<dim3(16, 16), 256, 0, stream>>>(Wzc,   W2,       512, 512, 1024);
  transpose_f2b<<<dim3(16, 16), 256, 0, stream>>>(Wemac, W2 + 512, 512, 512, 1024);

  // Xa = b @ Wa[:,512:]^T + ba ; Xd likewise.  (A fp32, B fp32 -> bf16 out)
  gemm_bt<0, true, false, false, true, true, false><<<dim3(4, 128), 256, 0, stream>>>(
      b, 0, 512, nullptr, Wa + 512, 0, 1024, ba, S1, 0, 16384, 512, 512, 1.f);
  gemm_bt<0, true, false, false, true, true, false><<<dim3(4, 128), 256, 0, stream>>>(
      b, 0, 512, nullptr, Wd + 512, 0, 1024, bd, S2, 0, 16384, 512, 512, 1.f);

  // Sequential EMA scan -> EMA (S3). 2 WGs, batch-split, no global sync.
  ema_recurrence<<<2, 1024, 0, stream>>>(Wa, Wd, S1, S2, b, S3);

  // b_ema = silu(ema @ Wout^T + bout) -> S1 (Xa dead)
  gemm_bt<1, true, false, false, false, true, false><<<dim3(4, 128), 256, 0, stream>>>(
      S3, 0, 512, nullptr, Wout, 0, 512, bout, S1, 0, 16384, 512, 512, 1.f);

  // q -> S2 (Xd dead); k -> S3 (EMA dead); v -> d_out (bf16, transposed).
  gemm_bt<0, true, false, false, false, true, false><<<dim3(4, 128), 256, 0, stream>>>(
      S1, 0, 512, nullptr, Wq, 0, 512, bq, S2, 0, 16384, 512, 512, 1.f);
  gemm_bt<0, true, false, false, false, true, false><<<dim3(4, 128), 256, 0, stream>>>(
      S1, 0, 512, nullptr, Wk, 0, 512, bk, S3, 0, 16384, 512, 512, 1.f);
  gemm_bt<0, true, false, true, false, true, false><<<dim3(4, 128), 256, 0, stream>>>(
      S1, 0, 512, nullptr, Wv, 0, 512, bv, OUTH, 0, 16384, 512, 512, 1.f);

  // Attention in 4 groups of 4 batches; scores reuse one 8MB buffer.
  for (int grp = 0; grp < 4; ++grp) {
    const long long go = (long long)grp * 4 * 1024 * 512;   // elem offset
    const long long gv = (long long)grp * 4 * 512 * 1024;   // V^T same size
    // scores = (q @ k^T)/sqrt(512)  [4 batches]
    gemm_bt<0, false, false, false, false, false, false><<<dim3(8, 8, 4), 256, 0, stream>>>(
        S2 + go, 1024 * 512, 512, nullptr, S3 + go, 1024 * 512, 512, nullptr,
        SC, 1024 * 1024, 1024, 1024, 512, 0.04419417382415922f);
    // softmax in place (4096 rows)
    softmax_rows_bf16<<<4096, 256, 0, stream>>>(SC);
    // Z_EMA = attn @ v -> over this group's Q region (Q dead for this group)
    gemm_bt<0, false, false, false, false, false, false><<<dim3(4, 8, 4), 256, 0, stream>>>(
        SC, 1024 * 1024, 1024, nullptr, OUTH + gv, 512 * 1024, 1024, nullptr,
        S2 + go, 1024 * 512, 1024, 512, 1024, 1.f);
  }

  // f = sigmoid(b_ema @ W_f^T + b_f) -> S3 (K dead)
  gemm_bt<2, true, false, false, false, true, false><<<dim3(4, 128), 256, 0, stream>>>(
      S1, 0, 512, nullptr, Wf, 0, 512, bfb, S3, 0, 16384, 512, 512, 1.f);

  // Z_EMA_f = f * Z_EMA  (in place on S2)
  mul_bf16<<<8192, 256, 0, stream>>>(S2, S3, 2097152);

  // Z_EMA_C = silu(Z_EMA_f @ W_z_C + b_ema @ W_EMA_c + b_C) -> d_out bf16
  // (V^T dead)
  gemm_bt<1, true, true, false, false, false, false><<<dim3(4, 128), 256, 0, stream>>>(
      S2, 0, 512, S1, W2, 0, 1024, bC, OUTH, 0, 16384, 512, 1024, 1.f);

  // i = sigmoid(b_ema @ W_i^T + b_i) -> S3 (f dead after mul)
  gemm_bt<2, true, false, false, false, true, false><<<dim3(4, 128), 256, 0, stream>>>(
      S1, 0, 512, nullptr, Wi, 0, 512, bi, S3, 0, 16384, 512, 512, 1.f);

  // B_h = i*Z_EMA_C + (1-i)*b -> S2 (Z_EMA_f dead)
  bh_blend<<<8192, 256, 0, stream>>>(S3, OUTH, b, S2, 2097152);

  // out = sigmoid(B_h @ W_o^T + b_o) -> d_out fp32 (overwrites scratch)
  gemm_bt<2, true, false, false, false, true, true><<<dim3(4, 128), 256, 0, stream>>>(
      S2, 0, 512, nullptr, Wo, 0, 512, bo, d_out, 0, 16384, 512, 512, 1.f);
}

// Round 7
// 6029.831 us; speedup vs baseline: 4.1275x; 4.1275x over previous
//
#include <hip/hip_runtime.h>
#include <math.h>

// ---------------------------------------------------------------------------
// Types / helpers
// ---------------------------------------------------------------------------
typedef short bf16x8 __attribute__((ext_vector_type(8)));
typedef float f32x4 __attribute__((ext_vector_type(4)));
typedef int   i32x4 __attribute__((ext_vector_type(4)));

#define DEV static __device__ __forceinline__

DEV float bf2f(unsigned short u) {
  union { unsigned int i; float f; } x;
  x.i = ((unsigned int)u) << 16;
  return x.f;
}
DEV unsigned short f2bf(float f) {  // round-to-nearest-even
  union { float f; unsigned int i; } x;
  x.f = f;
  unsigned int i = x.i;
  i += 0x7fffu + ((i >> 16) & 1u);
  return (unsigned short)(i >> 16);
}
// Load 8 contiguous fp32, convert to 8 bf16 packed in an i32x4.
DEV i32x4 load8_cvt(const float* p) {
  const float4 x = *(const float4*)p;
  const float4 y = *(const float4*)(p + 4);
  union { i32x4 v; unsigned short u[8]; } r;
  r.u[0] = f2bf(x.x); r.u[1] = f2bf(x.y); r.u[2] = f2bf(x.z); r.u[3] = f2bf(x.w);
  r.u[4] = f2bf(y.x); r.u[5] = f2bf(y.y); r.u[6] = f2bf(y.z); r.u[7] = f2bf(y.w);
  return r.v;
}
DEV bf16x8 load8_cvt_frag(const float* p) {
  union { i32x4 v; bf16x8 h; } u;
  u.v = load8_cvt(p);
  return u.h;
}

// ---------------------------------------------------------------------------
// Generic GEMM:  C[m,n] = act( escale*(A . B^T) + bias[n] ) ; MFMA in bf16.
// A: [M,K] row-major (lda); B: [N,K] row-major (ldb)  ("B^T" layout).
// AF32/BF32: operand stored fp32 (converted to bf16 in-register at staging).
// CF32: output fp32, else bf16.  bias is always fp32.
// 128x128 tile, BK=64, 4 waves, 4x4 MFMA 16x16x32, XOR-swizzled LDS.
// DUALA (bf16-A only): K=1024 split — kt<8 from A (lda), kt>=8 from A2 (512).
// TRANSC: C written V^T-style: idx=((row>>10)*512+col)*1024+(row&1023).
// ACT: 0=none 1=silu 2=sigmoid
// ---------------------------------------------------------------------------
template <int ACT, bool HASBIAS, bool DUALA, bool TRANSC,
          bool AF32, bool BF32, bool CF32>
__global__ __launch_bounds__(256) void gemm_bt(
    const void* __restrict__ A, long long sA, int lda,
    const unsigned short* __restrict__ A2,   // DUALA second source (bf16, ld=512)
    const void* __restrict__ B, long long sB, int ldb,
    const float* __restrict__ bias,
    void* __restrict__ Cout, long long sC,
    int M, int N, int K, float escale)
{
  __shared__ __align__(16) unsigned short Als[128 * 64];
  __shared__ __align__(16) unsigned short Bls[128 * 64];
  const int tid = threadIdx.x;
  const int l = tid & 63;
  const int w = tid >> 6;
  const int wrow = w >> 1, wcol = w & 1;
  const int lane15 = l & 15, quad = l >> 4;
  const long long tm0 = (long long)blockIdx.y * 128;
  const long long tn0 = (long long)blockIdx.x * 128;
  const long long zA = (long long)blockIdx.z * sA;
  const long long zB = (long long)blockIdx.z * sB;
  const float* Af          = (const float*)A;
  const unsigned short* Ah = (const unsigned short*)A;
  const float* Bf          = (const float*)B;
  const unsigned short* Bh = (const unsigned short*)B;

  f32x4 acc[4][4] = {};

  const int srow = tid >> 3;  // 0..31
  const int skb  = tid & 7;   // 0..7
  i32x4 ra[4], rb[4];

  auto gload = [&](int kt) {
    const long long k0 = (long long)kt * 64 + skb * 8;
#pragma unroll
    for (int it = 0; it < 4; ++it) {
      const int r = it * 32 + srow;
      if (DUALA && kt >= 8)
        ra[it] = *(const i32x4*)(A2 + (tm0 + r) * 512 + (k0 - 512));
      else if (AF32)
        ra[it] = load8_cvt(Af + zA + (tm0 + r) * lda + k0);
      else
        ra[it] = *(const i32x4*)(Ah + zA + (tm0 + r) * lda + k0);
      if (BF32)
        rb[it] = load8_cvt(Bf + zB + (tn0 + r) * ldb + k0);
      else
        rb[it] = *(const i32x4*)(Bh + zB + (tn0 + r) * ldb + k0);
    }
  };
  auto swrite = [&]() {
#pragma unroll
    for (int it = 0; it < 4; ++it) {
      const int r = it * 32 + srow;
      const int off = r * 64 + ((skb ^ (r & 7)) * 8);
      *(i32x4*)(Als + off) = ra[it];
      *(i32x4*)(Bls + off) = rb[it];
    }
  };

  gload(0);
  const int NK = K >> 6;
  for (int kt = 0; kt < NK; ++kt) {
    __syncthreads();
    swrite();
    __syncthreads();
    if (kt + 1 < NK) gload(kt + 1);
#pragma unroll
    for (int ks = 0; ks < 2; ++ks) {
      bf16x8 af[4], bfr[4];
#pragma unroll
      for (int ti = 0; ti < 4; ++ti) {
        const int m = wrow * 64 + ti * 16 + lane15;
        const int kb = ks * 4 + quad;
        af[ti] = *(const bf16x8*)(Als + m * 64 + ((kb ^ (m & 7)) * 8));
        const int n = wcol * 64 + ti * 16 + lane15;
        bfr[ti] = *(const bf16x8*)(Bls + n * 64 + ((kb ^ (n & 7)) * 8));
      }
#pragma unroll
      for (int ti = 0; ti < 4; ++ti)
#pragma unroll
        for (int tj = 0; tj < 4; ++tj)
          acc[ti][tj] = __builtin_amdgcn_mfma_f32_16x16x32_bf16(
              af[ti], bfr[tj], acc[ti][tj], 0, 0, 0);
    }
  }

  // Epilogue. C/D layout: col = lane&15, row = quad*4 + reg.
  const long long cb = (long long)blockIdx.z * sC;
#pragma unroll
  for (int tj = 0; tj < 4; ++tj) {
    const long long col = tn0 + wcol * 64 + tj * 16 + lane15;
    const float bvv = HASBIAS ? bias[col] : 0.f;
#pragma unroll
    for (int ti = 0; ti < 4; ++ti) {
#pragma unroll
      for (int r = 0; r < 4; ++r) {
        const long long row = tm0 + wrow * 64 + ti * 16 + quad * 4 + r;
        const long long idx =
            TRANSC ? (((row >> 10) * 512 + col) * 1024 + (row & 1023))
                   : (cb + row * (long long)N + col);
        float v = acc[ti][tj][r] * escale + bvv;
        if (ACT == 1) v = v / (1.f + __expf(-v));        // silu
        else if (ACT == 2) v = 1.f / (1.f + __expf(-v)); // sigmoid
        if (CF32) ((float*)Cout)[idx] = v;
        else      ((unsigned short*)Cout)[idx] = f2bf(v);
      }
    }
  }
}

// ---------------------------------------------------------------------------
// Transpose fp32 src -> bf16 dst with dst leading dim: dst[c*dld+r]=src[r*C+c]
// ---------------------------------------------------------------------------
__global__ __launch_bounds__(256) void transpose_f2b(
    const float* __restrict__ src, unsigned short* __restrict__ dst,
    int R, int C, int dld)
{
  __shared__ float tile[32][33];
  const int c0 = blockIdx.x * 32, r0 = blockIdx.y * 32;
  const int tx = threadIdx.x & 31, ty = threadIdx.x >> 5;
  for (int i = ty; i < 32; i += 8)
    tile[i][tx] = src[(long long)(r0 + i) * C + c0 + tx];
  __syncthreads();
  for (int i = ty; i < 32; i += 8)
    dst[(long long)(c0 + i) * dld + r0 + tx] = f2bf(tile[tx][i]);
}

// ---------------------------------------------------------------------------
// In-place row softmax over 1024 bf16 cols (scale applied upstream).
// Each thread owns its own ushort4 of its own row -> in-place is race-free.
// ---------------------------------------------------------------------------
__global__ __launch_bounds__(256) void softmax_rows_bf16(
    unsigned short* __restrict__ S)
{
  const long long row = blockIdx.x;
  const int tid = threadIdx.x;
  const ushort4 u = ((const ushort4*)(S + row * 1024))[tid];
  const float a = bf2f(u.x), b = bf2f(u.y), c = bf2f(u.z), d = bf2f(u.w);
  float mx = fmaxf(fmaxf(a, b), fmaxf(c, d));
#pragma unroll
  for (int o = 32; o > 0; o >>= 1) mx = fmaxf(mx, __shfl_xor(mx, o));
  __shared__ float redm[4], reds[4];
  const int w = tid >> 6;
  if ((tid & 63) == 0) redm[w] = mx;
  __syncthreads();
  mx = fmaxf(fmaxf(redm[0], redm[1]), fmaxf(redm[2], redm[3]));
  const float e0 = __expf(a - mx), e1 = __expf(b - mx);
  const float e2 = __expf(c - mx), e3 = __expf(d - mx);
  float s = e0 + e1 + e2 + e3;
#pragma unroll
  for (int o = 32; o > 0; o >>= 1) s += __shfl_xor(s, o);
  if ((tid & 63) == 0) reds[w] = s;
  __syncthreads();
  s = reds[0] + reds[1] + reds[2] + reds[3];
  const float inv = 1.f / s;
  ushort4 o4;
  o4.x = f2bf(e0 * inv); o4.y = f2bf(e1 * inv);
  o4.z = f2bf(e2 * inv); o4.w = f2bf(e3 * inv);
  ((ushort4*)(S + row * 1024))[tid] = o4;
}

// ---------------------------------------------------------------------------
// In-place z *= f (bf16, 4/thread). Per-element ownership -> race-free.
// ---------------------------------------------------------------------------
__global__ __launch_bounds__(256) void mul_bf16(
    unsigned short* __restrict__ z, const unsigned short* __restrict__ f, int n4)
{
  const int idx = blockIdx.x * 256 + threadIdx.x;
  if (idx >= n4) return;
  ushort4 zv = ((const ushort4*)z)[idx];
  const ushort4 fv = ((const ushort4*)f)[idx];
  zv.x = f2bf(bf2f(zv.x) * bf2f(fv.x));
  zv.y = f2bf(bf2f(zv.y) * bf2f(fv.y));
  zv.z = f2bf(bf2f(zv.z) * bf2f(fv.z));
  zv.w = f2bf(bf2f(zv.w) * bf2f(fv.w));
  ((ushort4*)z)[idx] = zv;
}

// ---------------------------------------------------------------------------
// B_h = i*ZC + (1-i)*b   (i,ZC bf16; b fp32; out bf16), 4 elems/thread
// ---------------------------------------------------------------------------
__global__ __launch_bounds__(256) void bh_blend(
    const unsigned short* __restrict__ ib, const unsigned short* __restrict__ zc,
    const float* __restrict__ bsrc, unsigned short* __restrict__ out, int n4)
{
  const int idx = blockIdx.x * 256 + threadIdx.x;
  if (idx >= n4) return;
  const ushort4 iv = ((const ushort4*)ib)[idx];
  const ushort4 zv = ((const ushort4*)zc)[idx];
  const float4 bv = ((const float4*)bsrc)[idx];
  ushort4 o;
  const float i0 = bf2f(iv.x), i1 = bf2f(iv.y), i2 = bf2f(iv.z), i3 = bf2f(iv.w);
  o.x = f2bf(i0 * bf2f(zv.x) + (1.f - i0) * bv.x);
  o.y = f2bf(i1 * bf2f(zv.y) + (1.f - i1) * bv.y);
  o.z = f2bf(i2 * bf2f(zv.z) + (1.f - i2) * bv.z);
  o.w = f2bf(i3 * bf2f(zv.w) + (1.f - i3) * bv.w);
  ((ushort4*)out)[idx] = o;
}

// ---------------------------------------------------------------------------
// EMA recurrence — round-5 structure (best measured: 6.13us/step), round-7
// sync protocol. 8 persistent WGs x 512 threads, WG j owns cols
// [j*64, j*64+64). 8 waves: gate g=w>>2 (0=alpha/Wa, 1=delta/Wd), 16-col
// tile t4=w&3. Weight fragments (fp32->bf16) register-resident (88 VGPRs,
// fits the 2-waves/SIMD budget — round-6's 1024-thr variant spilled at the
// 128-VGPR cap and regressed 4x).
//
// Protocol: prevbuf written with RELAXED AGENT-scope atomic stores (atomics
// complete at the agent coherence point -> no dirty local-L2 lines, no
// buffer_wbl2 needed). __syncthreads() drains every wave's vmcnt (compiler
// emits s_waitcnt vmcnt(0) before s_barrier), so data is globally visible
// before tid0 publishes the flag with a RELAXED store (round-5 used RELEASE,
// which emits a full buffer_wbl2 L2-writeback walk every step — suspected
// ~3-4us of the 6.13us step). Consumer: RELAXED polls (no per-poll inv), one
// acquire fence (buffer_inv) per step, then plain prevbuf loads.
// ---------------------------------------------------------------------------
__global__ __launch_bounds__(512) void ema_recurrence(
    const float* __restrict__ Wa,            // fp32 [512][1024], k 0..511 used
    const float* __restrict__ Wd,
    const unsigned short* __restrict__ Xa,   // [16,1024,512] bf16 (bias folded)
    const unsigned short* __restrict__ Xd,
    const float* __restrict__ Bin,           // b: [16,1024,512] fp32
    unsigned short* __restrict__ ema,        // out: [16,1024,512] bf16
    unsigned short* __restrict__ prevbuf,    // [2][16][512] bf16
    int* __restrict__ flags)                 // [8]
{
  const int j = blockIdx.x;
  const int tid = threadIdx.x;
  const int l = tid & 63;
  const int w = tid >> 6;          // 0..7
  const int n0 = j * 64;
  const int g = w >> 2;            // 0=alpha, 1=delta
  const int t4 = w & 3;            // 16-col tile within the 64
  const int lane15 = l & 15;
  const int quad = l >> 4;
  const int ncol = n0 + t4 * 16 + lane15;
  const float* Wsel = g ? Wd : Wa;

  // B-operand frags: B^T[n=lane&15][k=quad*8+j], 16 k-steps of 32.
  bf16x8 wf[16];
#pragma unroll
  for (int s = 0; s < 16; ++s) {
    const int k = s * 32 + quad * 8;
    wf[s] = load8_cvt_frag(Wsel + (long long)ncol * 1024 + k);
  }

  __shared__ float lds_g[2][16][64];

  const int ei = tid >> 5;         // batch row 0..15
  const int ec = (tid & 31) * 2;   // local col pair 0..62
  const int gn = n0 + ec;
  float pv0 = 0.f, pv1 = 0.f;      // fp32 prev (exact, local)

  for (int t = 0; t < 1024; ++t) {
    const long long eidx = ((long long)ei * 1024 + t) * 512 + gn;
    const unsigned int xau = *(const unsigned int*)(Xa + eidx);  // before spin
    const unsigned int xdu = *(const unsigned int*)(Xd + eidx);
    const float2 btv = *(const float2*)(Bin + eidx);

    f32x4 acc = {0.f, 0.f, 0.f, 0.f};
    if (t > 0) {
      // RELAXED coherent polls (no per-poll invalidate)
      int guard = 0;
      for (;;) {
        const int fv = __hip_atomic_load(&flags[l & 7], __ATOMIC_RELAXED,
                                         __HIP_MEMORY_SCOPE_AGENT);
        if (__all(fv >= t)) break;
        if (++guard > (1 << 18)) break;  // bail out instead of hanging
        __builtin_amdgcn_s_sleep(1);
      }
      // single acquire per step: invalidate stale L1/L2 copies of prevbuf
      __builtin_amdgcn_fence(__ATOMIC_ACQUIRE, "agent");

      const unsigned short* pb = prevbuf + ((t - 1) & 1) * (16 * 512);
      bf16x8 af[16];  // A[m=lane&15][k=quad*8+j]
#pragma unroll
      for (int s = 0; s < 16; ++s) {
        const int k = s * 32 + quad * 8;
        af[s] = *(const bf16x8*)(pb + lane15 * 512 + k);
      }
#pragma unroll
      for (int s = 0; s < 16; ++s)
        acc = __builtin_amdgcn_mfma_f32_16x16x32_bf16(af[s], wf[s], acc, 0, 0, 0);
    }
    // exchange gate tiles through LDS (C layout: col=lane&15, row=quad*4+r)
#pragma unroll
    for (int r = 0; r < 4; ++r)
      lds_g[g][quad * 4 + r][t4 * 16 + lane15] = acc[r];
    __syncthreads();

    float a0 = lds_g[0][ei][ec]     + bf2f((unsigned short)(xau & 0xffffu));
    float a1 = lds_g[0][ei][ec + 1] + bf2f((unsigned short)(xau >> 16));
    float d0 = lds_g[1][ei][ec]     + bf2f((unsigned short)(xdu & 0xffffu));
    float d1 = lds_g[1][ei][ec + 1] + bf2f((unsigned short)(xdu >> 16));
    a0 = tanhf(a0); a1 = tanhf(a1);
    d0 = tanhf(d0); d1 = tanhf(d1);
    const float z0 = a0 * btv.x + (1.f - a0 * d0) * pv0;
    const float z1 = a1 * btv.y + (1.f - a1 * d1) * pv1;
    const float e0 = 1.f / (1.f + __expf(-z0));
    const float e1 = 1.f / (1.f + __expf(-z1));
    pv0 = e0; pv1 = e1;
    const unsigned int packed =
        (unsigned int)f2bf(e0) | ((unsigned int)f2bf(e1) << 16);
    // ema: non-temporal (don't dirty L2)
    __builtin_nontemporal_store(packed, (unsigned int*)(ema + eidx));
    // prevbuf: RELAXED AGENT atomic store -> completes at coherence point,
    // keeps local L2 clean (no wbl2 required on release).
    __hip_atomic_store(
        (unsigned int*)(prevbuf + (t & 1) * (16 * 512) + (long long)ei * 512 + gn),
        packed, __ATOMIC_RELAXED, __HIP_MEMORY_SCOPE_AGENT);
    // __syncthreads drains each wave's vmcnt (s_waitcnt vmcnt(0) before
    // s_barrier) -> all atomic stores globally visible; then a RELAXED flag
    // publish suffices (no wbl2).
    __syncthreads();
    if (tid == 0)
      __hip_atomic_store(&flags[j], t + 1, __ATOMIC_RELAXED,
                         __HIP_MEMORY_SCOPE_AGENT);
  }
}

// ---------------------------------------------------------------------------
// Host. ALL inputs fp32, output fp32. Intermediates bf16.
// Workspace peak ~57.1 MB; d_out (32MB fp32) doubles as bf16 scratch for
// V^T then Z_EMA_C before the final fp32 GEMM overwrites it.
// Slot lifetimes:
//   S1: Xa  -> b_ema
//   S2: Xd  -> Q  -> Z_EMA (per-group) -> B_h
//   S3: EMA -> K  -> f -> i
//   SC (8MB): scores for 4 batches at a time
// ---------------------------------------------------------------------------
extern "C" void kernel_launch(void* const* d_in, const int* in_sizes, int n_in,
                              void* d_out, int out_size, void* d_ws, size_t ws_size,
                              hipStream_t stream)
{
  (void)in_sizes; (void)n_in; (void)out_size; (void)ws_size;
  typedef const float* cfp;
  cfp b     = (cfp)d_in[0];
  cfp Wq    = (cfp)d_in[1];  cfp bq   = (cfp)d_in[2];
  cfp Wk    = (cfp)d_in[3];  cfp bk   = (cfp)d_in[4];
  cfp Wv    = (cfp)d_in[5];  cfp bv   = (cfp)d_in[6];
  cfp Wa    = (cfp)d_in[7];  cfp ba   = (cfp)d_in[8];
  cfp Wd    = (cfp)d_in[9];  cfp bd   = (cfp)d_in[10];
  cfp Wout  = (cfp)d_in[11]; cfp bout = (cfp)d_in[12];
  cfp Wf    = (cfp)d_in[13]; cfp bfb  = (cfp)d_in[14];
  cfp Wemac = (cfp)d_in[15];
  cfp Wzc   = (cfp)d_in[16]; cfp bC   = (cfp)d_in[17];
  cfp Wi    = (cfp)d_in[18]; cfp bi   = (cfp)d_in[19];
  cfp Wo    = (cfp)d_in[20]; cfp bo   = (cfp)d_in[21];

  char* ws = (char*)d_ws;
  const size_t MB = 1024ull * 1024ull;
  typedef unsigned short* bfp;
  bfp S1    = (bfp)(ws + 0);        // 16MB
  bfp S2    = (bfp)(ws + 16 * MB);  // 16MB
  bfp S3    = (bfp)(ws + 32 * MB);  // 16MB
  bfp SC    = (bfp)(ws + 48 * MB);  // 8MB (scores, 4 batches)
  bfp W2    = (bfp)(ws + 56 * MB);  // 1MB combined bf16 [512n][1024k]
  bfp PREV  = (bfp)(ws + 57 * MB);  // 32KB
  int* FLAGS= (int*)(ws + 57 * MB + 64 * 1024);
  bfp OUTH  = (bfp)d_out;           // bf16 scratch view: V^T, then Z_EMA_C

  hipMemsetAsync(FLAGS, 0, 256, stream);

  // Combined weight (bf16) for the dual-A GEMM: W2[n][k<512]=Wzc[k][n],
  // W2[n][512+k]=Wemac[k][n].
  transpose_f2b<<<dim3(16, 16), 256, 0, stream>>>(Wzc,   W2,       512, 512, 1024);
  transpose_f2b<<<dim3(16, 16), 256, 0, stream>>>(Wemac, W2 + 512, 512, 512, 1024);

  // Xa = b @ Wa[:,512:]^T + ba ; Xd likewise.  (A fp32, B fp32 -> bf16 out)
  gemm_bt<0, true, false, false, true, true, false><<<dim3(4, 128), 256, 0, stream>>>(
      b, 0, 512, nullptr, Wa + 512, 0, 1024, ba, S1, 0, 16384, 512, 512, 1.f);
  gemm_bt<0, true, false, false, true, true, false><<<dim3(4, 128), 256, 0, stream>>>(
      b, 0, 512, nullptr, Wd + 512, 0, 1024, bd, S2, 0, 16384, 512, 512, 1.f);

  // Sequential EMA scan -> EMA (S3). 8 WGs, column-split.
  ema_recurrence<<<8, 512, 0, stream>>>(Wa, Wd, S1, S2, b, S3, PREV, FLAGS);

  // b_ema = silu(ema @ Wout^T + bout) -> S1 (Xa dead)
  gemm_bt<1, true, false, false, false, true, false><<<dim3(4, 128), 256, 0, stream>>>(
      S3, 0, 512, nullptr, Wout, 0, 512, bout, S1, 0, 16384, 512, 512, 1.f);

  // q -> S2 (Xd dead); k -> S3 (EMA dead); v -> d_out (bf16, transposed).
  gemm_bt<0, true, false, false, false, true, false><<<dim3(4, 128), 256, 0, stream>>>(
      S1, 0, 512, nullptr, Wq, 0, 512, bq, S2, 0, 16384, 512, 512, 1.f);
  gemm_bt<0, true, false, false, false, true, false><<<dim3(4, 128), 256, 0, stream>>>(
      S1, 0, 512, nullptr, Wk, 0, 512, bk, S3, 0, 16384, 512, 512, 1.f);
  gemm_bt<0, true, false, true, false, true, false><<<dim3(4, 128), 256, 0, stream>>>(
      S1, 0, 512, nullptr, Wv, 0, 512, bv, OUTH, 0, 16384, 512, 512, 1.f);

  // Attention in 4 groups of 4 batches; scores reuse one 8MB buffer.
  for (int grp = 0; grp < 4; ++grp) {
    const long long go = (long long)grp * 4 * 1024 * 512;   // elem offset
    const long long gv = (long long)grp * 4 * 512 * 1024;   // V^T same size
    // scores = (q @ k^T)/sqrt(512)  [4 batches]
    gemm_bt<0, false, false, false, false, false, false><<<dim3(8, 8, 4), 256, 0, stream>>>(
        S2 + go, 1024 * 512, 512, nullptr, S3 + go, 1024 * 512, 512, nullptr,
        SC, 1024 * 1024, 1024, 1024, 512, 0.04419417382415922f);
    // softmax in place (4096 rows)
    softmax_rows_bf16<<<4096, 256, 0, stream>>>(SC);
    // Z_EMA = attn @ v -> over this group's Q region (Q dead for this group)
    gemm_bt<0, false, false, false, false, false, false><<<dim3(4, 8, 4), 256, 0, stream>>>(
        SC, 1024 * 1024, 1024, nullptr, OUTH + gv, 512 * 1024, 1024, nullptr,
        S2 + go, 1024 * 512, 1024, 512, 1024, 1.f);
  }

  // f = sigmoid(b_ema @ W_f^T + b_f) -> S3 (K dead)
  gemm_bt<2, true, false, false, false, true, false><<<dim3(4, 128), 256, 0, stream>>>(
      S1, 0, 512, nullptr, Wf, 0, 512, bfb, S3, 0, 16384, 512, 512, 1.f);

  // Z_EMA_f = f * Z_EMA  (in place on S2)
  mul_bf16<<<8192, 256, 0, stream>>>(S2, S3, 2097152);

  // Z_EMA_C = silu(Z_EMA_f @ W_z_C + b_ema @ W_EMA_c + b_C) -> d_out bf16
  // (V^T dead)
  gemm_bt<1, true, true, false, false, false, false><<<dim3(4, 128), 256, 0, stream>>>(
      S2, 0, 512, S1, W2, 0, 1024, bC, OUTH, 0, 16384, 512, 1024, 1.f);

  // i = sigmoid(b_ema @ W_i^T + b_i) -> S3 (f dead after mul)
  gemm_bt<2, true, false, false, false, true, false><<<dim3(4, 128), 256, 0, stream>>>(
      S1, 0, 512, nullptr, Wi, 0, 512, bi, S3, 0, 16384, 512, 512, 1.f);

  // B_h = i*Z_EMA_C + (1-i)*b -> S2 (Z_EMA_f dead)
  bh_blend<<<8192, 256, 0, stream>>>(S3, OUTH, b, S2, 2097152);

  // out = sigmoid(B_h @ W_o^T + b_o) -> d_out fp32 (overwrites scratch)
  gemm_bt<2, true, false, false, false, true, true><<<dim3(4, 128), 256, 0, stream>>>(
      S2, 0, 512, nullptr, Wo, 0, 512, bo, d_out, 0, 16384, 512, 512, 1.f);
}